// Round 1
// baseline (760.377 us; speedup 1.0000x reference)
//
#include <hip/hip_runtime.h>
#include <hip/hip_bf16.h>
#include <math.h>

#define T_SEQ 4096
#define C_DIM 2048
#define NH 16
#define NKV 4
#define HD 128

typedef __attribute__((ext_vector_type(4))) float f32x4;
typedef __attribute__((ext_vector_type(8))) short s16x8;
typedef __hip_bfloat16 bf16;

__device__ __forceinline__ float softcap50(float s) {
  float x = s * 0.02f;
  x = fminf(fmaxf(x, -15.f), 15.f);
  float e = __expf(2.f * x);
  return 50.f * ((e - 1.f) / (e + 1.f));
}

// ---------------- fp32 -> bf16 elementwise convert ----------------
__global__ void k_cvt_bf16(const float* __restrict__ in, bf16* __restrict__ out, int n4) {
  int i = blockIdx.x * blockDim.x + threadIdx.x;
  if (i < n4) {
    float4 v = ((const float4*)in)[i];
    union { bf16 h[4]; short4 s; } u;
    u.h[0] = __float2bfloat16(v.x);
    u.h[1] = __float2bfloat16(v.y);
    u.h[2] = __float2bfloat16(v.z);
    u.h[3] = __float2bfloat16(v.w);
    ((short4*)out)[i] = u.s;
  }
}

// ---------------- transpose + convert: in [K][N] f32 -> out [N][K] bf16 ----
__global__ void k_transpose_cvt(const float* __restrict__ in, bf16* __restrict__ out,
                                int K, int N) {
  __shared__ float tile[64][65];
  int n0 = blockIdx.x * 64, k0 = blockIdx.y * 64;
  int c = threadIdx.x & 63, r0 = threadIdx.x >> 6;
#pragma unroll
  for (int it = 0; it < 16; ++it) {
    int r = it * 4 + r0;
    tile[r][c] = in[(size_t)(k0 + r) * N + (n0 + c)];
  }
  __syncthreads();
#pragma unroll
  for (int it = 0; it < 16; ++it) {
    int r = it * 4 + r0;
    out[(size_t)(n0 + r) * K + (k0 + c)] = __float2bfloat16(tile[c][r]);
  }
}

// ---------------- GEMM: C[M][N] = A[M][K] * Bt[N][K]^T  (bf16 in, f32 out) --
// 128x128 tile, BK=64, 256 threads (4 waves as 2x2, each 64x64 = 4x4 frags)
__global__ __launch_bounds__(256) void k_gemm_bt(
    const bf16* __restrict__ A, const bf16* __restrict__ Bt, float* __restrict__ C,
    int M, int N, int K) {
  __shared__ __align__(16) bf16 As[128 * 64];
  __shared__ __align__(16) bf16 Bs[128 * 64];
  int nTilesN = N >> 7;
  int bm = blockIdx.x / nTilesN, bn = blockIdx.x % nTilesN;
  int row0 = bm * 128, col0 = bn * 128;
  int tid = threadIdx.x, lane = tid & 63, wid = tid >> 6;
  int wm = wid >> 1, wn = wid & 1;
  int l15 = lane & 15, l4 = lane >> 4;
  f32x4 acc[4][4] = {};
  int srow = lane >> 3;      // 0..7 within 8-row chunk
  int schk = lane & 7;       // 16B chunk within row
  for (int kt = 0; kt < (K >> 6); ++kt) {
    const bf16* Ab = A + (size_t)row0 * K + kt * 64;
    const bf16* Bb = Bt + (size_t)col0 * K + kt * 64;
    int4 va[4], vb[4];
#pragma unroll
    for (int it = 0; it < 4; ++it) {
      int t = wid * 4 + it;
      va[it] = *(const int4*)(Ab + (size_t)(8 * t + srow) * K + schk * 8);
      vb[it] = *(const int4*)(Bb + (size_t)(8 * t + srow) * K + schk * 8);
    }
#pragma unroll
    for (int it = 0; it < 4; ++it) {
      int t = wid * 4 + it;
      *(int4*)(As + t * 512 + lane * 8) = va[it];
      *(int4*)(Bs + t * 512 + lane * 8) = vb[it];
    }
    __syncthreads();
#pragma unroll
    for (int ks = 0; ks < 2; ++ks) {
      s16x8 af[4], bfr[4];
#pragma unroll
      for (int m = 0; m < 4; ++m)
        af[m] = *(const s16x8*)(As + (wm * 64 + m * 16 + l15) * 64 + ks * 32 + l4 * 8);
#pragma unroll
      for (int n = 0; n < 4; ++n)
        bfr[n] = *(const s16x8*)(Bs + (wn * 64 + n * 16 + l15) * 64 + ks * 32 + l4 * 8);
#pragma unroll
      for (int m = 0; m < 4; ++m)
#pragma unroll
        for (int n = 0; n < 4; ++n)
          acc[m][n] = __builtin_amdgcn_mfma_f32_16x16x32_bf16(af[m], bfr[n], acc[m][n], 0, 0, 0);
    }
    __syncthreads();
  }
#pragma unroll
  for (int m = 0; m < 4; ++m)
#pragma unroll
    for (int n = 0; n < 4; ++n)
#pragma unroll
      for (int r = 0; r < 4; ++r) {
        int rr = row0 + wm * 64 + m * 16 + l4 * 4 + r;
        int cc = col0 + wn * 64 + n * 16 + l15;
        C[(size_t)rr * N + cc] = acc[m][n][r];
      }
}

// ---------------- RMSNorm + RoPE prep: one wave per (t, head) row ----------
// src [T][rowStride] f32, head h at col h*128 -> out [nh][T][128] bf16
__global__ void k_qkprep(const float* __restrict__ src, int rowStride, int nh,
                         const float* __restrict__ w, float outScale,
                         bf16* __restrict__ out) {
  int idx = blockIdx.x * 4 + (threadIdx.x >> 6);
  int lane = threadIdx.x & 63;
  int t = idx / nh;
  int h = idx & (nh - 1);
  const float* s = src + (size_t)t * rowStride + h * HD;
  float x1 = s[lane], x2 = s[lane + 64];
  float ss = x1 * x1 + x2 * x2;
#pragma unroll
  for (int m = 1; m < 64; m <<= 1) ss += __shfl_xor(ss, m);
  float rs = rsqrtf(ss * (1.0f / 128.0f) + 1e-6f);
  x1 *= rs * w[lane];
  x2 *= rs * w[lane + 64];
  float invf = expf(-(float)lane * 0.14391156831212787f);  // ln(10000)/64
  float fr = (float)t * invf;
  float sv, cv;
  sincosf(fr, &sv, &cv);
  float y1 = (x1 * cv + x2 * sv) * outScale;
  float y2 = (-x1 * sv + x2 * cv) * outScale;
  bf16* dst = out + ((size_t)h * T_SEQ + t) * HD;
  dst[lane] = __float2bfloat16(y1);
  dst[lane + 64] = __float2bfloat16(y2);
}

// ---------------- V transpose: kv32[t][512 + hk*128 + d] -> Vt[hk][d][t] ----
__global__ void k_vtrans(const float* __restrict__ kv32, bf16* __restrict__ Vt) {
  __shared__ float tile[64][65];
  int t0 = blockIdx.x * 64, d0 = blockIdx.y * 64, hk = blockIdx.z;
  int c = threadIdx.x & 63, r0 = threadIdx.x >> 6;
#pragma unroll
  for (int it = 0; it < 16; ++it) {
    int r = it * 4 + r0;
    tile[r][c] = kv32[(size_t)(t0 + r) * 1024 + 512 + hk * 128 + d0 + c];
  }
  __syncthreads();
#pragma unroll
  for (int it = 0; it < 16; ++it) {
    int r = it * 4 + r0;
    Vt[((size_t)hk * 128 + d0 + r) * T_SEQ + (t0 + c)] = __float2bfloat16(tile[c][r]);
  }
}

// ---------------- causal GQA flash attention --------------------------------
// Qb [NH][T][128] (pre-scaled by 1/sqrt(128)), Kb [NKV][T][128], Vt [NKV][128][T]
// Y [T][C] bf16. Block: 64 q-rows x 1 head; 4 waves x 16 q-rows; kv tile = 64.
__global__ __launch_bounds__(256) void k_attn(
    const bf16* __restrict__ Qb, const bf16* __restrict__ Kb,
    const bf16* __restrict__ Vt, bf16* __restrict__ Y) {
  __shared__ __align__(16) bf16 Ks[64 * 128];   // [kv][d], chunk-swizzled
  __shared__ __align__(16) bf16 Vs[128 * 64];   // [d][kv], chunk-swizzled
  __shared__ __align__(16) bf16 Pl[4][16 * 64]; // wave-private P, swizzled
  int qb = blockIdx.x, h = blockIdx.y, hk = h >> 2;
  int tid = threadIdx.x, lane = tid & 63, w = tid >> 6;
  int l15 = lane & 15, l4 = lane >> 4;
  int qrow0 = qb * 64 + w * 16;

  s16x8 aq[4];
  {
    const bf16* Qp = Qb + ((size_t)h * T_SEQ + qrow0 + l15) * HD + l4 * 8;
#pragma unroll
    for (int ks = 0; ks < 4; ++ks) aq[ks] = *(const s16x8*)(Qp + ks * 32);
  }
  float mrow[4] = {-INFINITY, -INFINITY, -INFINITY, -INFINITY};
  float lrow[4] = {0.f, 0.f, 0.f, 0.f};
  f32x4 o[8] = {};
  const bf16* Kbase = Kb + (size_t)hk * T_SEQ * HD;
  const bf16* Vbase = Vt + (size_t)hk * HD * T_SEQ;
  bf16* Pw = &Pl[w][0];

  for (int kt = 0; kt <= qb; ++kt) {
    int kv0 = kt * 64;
    // stage K [64][128]: instr t covers 4 rows x 16 chunks; lane -> row 4t+l4, chunk l15
    // stage Vt [128][64]: instr t covers 8 rows x 8 chunks; lane -> row 8t+lane/8, chunk lane&7
    int4 vk[4], vv[4];
#pragma unroll
    for (int it = 0; it < 4; ++it) {
      int t = w * 4 + it;
      int r = 4 * t + l4;
      int scb = l15 ^ (r & 7);  // swizzled source chunk (low 3 bits)
      vk[it] = *(const int4*)(Kbase + (size_t)(kv0 + r) * HD + scb * 8);
      int d = 8 * t + (lane >> 3);
      int scb2 = (lane & 7) ^ (d & 7);
      vv[it] = *(const int4*)(Vbase + (size_t)d * T_SEQ + kv0 + scb2 * 8);
    }
#pragma unroll
    for (int it = 0; it < 4; ++it) {
      int t = w * 4 + it;
      *(int4*)(Ks + t * 512 + lane * 8) = vk[it];
      *(int4*)(Vs + t * 512 + lane * 8) = vv[it];
    }
    __syncthreads();

    // S = Q K^T : 4 kv-frags x 4 k-slices
    f32x4 sf[4] = {};
#pragma unroll
    for (int n = 0; n < 4; ++n) {
      int r = n * 16 + l15;
#pragma unroll
      for (int ks = 0; ks < 4; ++ks) {
        int c = (ks * 4 + l4) ^ (r & 7);
        s16x8 bk = *(const s16x8*)(Ks + r * 128 + c * 8);
        sf[n] = __builtin_amdgcn_mfma_f32_16x16x32_bf16(aq[ks], bk, sf[n], 0, 0, 0);
      }
    }
    // softcap + causal mask
    float pv[4][4];
#pragma unroll
    for (int n = 0; n < 4; ++n) {
      int kvidx = kv0 + n * 16 + l15;
#pragma unroll
      for (int r = 0; r < 4; ++r) {
        int qidx = qrow0 + l4 * 4 + r;
        float svv = softcap50(sf[n][r]);
        pv[n][r] = (kvidx > qidx) ? -INFINITY : svv;
      }
    }
    // online softmax (rows live in 16-lane groups; 4 rows/lane via reg index)
#pragma unroll
    for (int r = 0; r < 4; ++r) {
      float rm = fmaxf(fmaxf(pv[0][r], pv[1][r]), fmaxf(pv[2][r], pv[3][r]));
      rm = fmaxf(rm, __shfl_xor(rm, 1));
      rm = fmaxf(rm, __shfl_xor(rm, 2));
      rm = fmaxf(rm, __shfl_xor(rm, 4));
      rm = fmaxf(rm, __shfl_xor(rm, 8));
      float mnew = fmaxf(mrow[r], rm);
      float scale = __expf(mrow[r] - mnew);
      float psum = 0.f;
#pragma unroll
      for (int n = 0; n < 4; ++n) {
        float p = __expf(pv[n][r] - mnew);
        pv[n][r] = p;
        psum += p;
      }
      psum += __shfl_xor(psum, 1);
      psum += __shfl_xor(psum, 2);
      psum += __shfl_xor(psum, 4);
      psum += __shfl_xor(psum, 8);
      lrow[r] = lrow[r] * scale + psum;
      mrow[r] = mnew;
#pragma unroll
      for (int nf = 0; nf < 8; ++nf) o[nf][r] *= scale;
    }
    // P -> wave-private LDS (swizzled), read back as A-operand frags
#pragma unroll
    for (int n = 0; n < 4; ++n) {
      int col = n * 16 + l15;
#pragma unroll
      for (int r = 0; r < 4; ++r) {
        int row = l4 * 4 + r;
        int ch = (col >> 3) ^ (row & 7);
        Pw[row * 64 + ch * 8 + (col & 7)] = __float2bfloat16(pv[n][r]);
      }
    }
#pragma unroll
    for (int ks = 0; ks < 2; ++ks) {
      int pch = (ks * 4 + l4) ^ (l15 & 7);
      s16x8 pa = *(const s16x8*)(Pw + l15 * 64 + pch * 8);
#pragma unroll
      for (int nf = 0; nf < 8; ++nf) {
        int vr = nf * 16 + l15;
        int vch = (ks * 4 + l4) ^ (vr & 7);
        s16x8 bv = *(const s16x8*)(Vs + vr * 64 + vch * 8);
        o[nf] = __builtin_amdgcn_mfma_f32_16x16x32_bf16(pa, bv, o[nf], 0, 0, 0);
      }
    }
    __syncthreads();
  }
#pragma unroll
  for (int nf = 0; nf < 8; ++nf)
#pragma unroll
    for (int r = 0; r < 4; ++r) {
      int qidx = qrow0 + l4 * 4 + r;
      int d = nf * 16 + l15;
      Y[(size_t)qidx * C_DIM + h * HD + d] = __float2bfloat16(o[nf][r] / lrow[r]);
    }
}

extern "C" void kernel_launch(void* const* d_in, const int* in_sizes, int n_in,
                              void* d_out, int out_size, void* d_ws, size_t ws_size,
                              hipStream_t stream) {
  const float* x = (const float*)d_in[0];
  const float* Wq = (const float*)d_in[1];
  const float* Wkv = (const float*)d_in[2];
  const float* Wc = (const float*)d_in[3];
  const float* qnw = (const float*)d_in[4];
  const float* knw = (const float*)d_in[5];
  float* out = (float*)d_out;

  char* ws = (char*)d_ws;
  size_t off = 0;
  auto alloc = [&](size_t b) { void* p = ws + off; off += (b + 255) & ~(size_t)255; return p; };

  bf16* xb = (bf16*)alloc((size_t)T_SEQ * C_DIM * 2);
  bf16* WqT = (bf16*)alloc((size_t)C_DIM * C_DIM * 2);
  bf16* WkvT = (bf16*)alloc((size_t)1024 * C_DIM * 2);
  bf16* WcT = (bf16*)alloc((size_t)C_DIM * C_DIM * 2);
  float* kv32 = (float*)alloc((size_t)T_SEQ * 1024 * 4);
  bf16* Qb = (bf16*)alloc((size_t)NH * T_SEQ * HD * 2);
  bf16* Kb = (bf16*)alloc((size_t)NKV * T_SEQ * HD * 2);
  bf16* Vt = (bf16*)alloc((size_t)NKV * HD * T_SEQ * 2);
  bf16* Yb = (bf16*)alloc((size_t)T_SEQ * C_DIM * 2);
  float* q32 = out;  // reuse the 32MB output buffer as scratch for pre-norm q

  k_cvt_bf16<<<(T_SEQ * C_DIM / 4 + 255) / 256, 256, 0, stream>>>(x, xb, T_SEQ * C_DIM / 4);
  k_transpose_cvt<<<dim3(C_DIM / 64, C_DIM / 64), 256, 0, stream>>>(Wq, WqT, C_DIM, C_DIM);
  k_transpose_cvt<<<dim3(1024 / 64, C_DIM / 64), 256, 0, stream>>>(Wkv, WkvT, C_DIM, 1024);
  k_transpose_cvt<<<dim3(C_DIM / 64, C_DIM / 64), 256, 0, stream>>>(Wc, WcT, C_DIM, C_DIM);

  k_gemm_bt<<<(T_SEQ / 128) * (C_DIM / 128), 256, 0, stream>>>(xb, WqT, q32, T_SEQ, C_DIM, C_DIM);
  k_gemm_bt<<<(T_SEQ / 128) * (1024 / 128), 256, 0, stream>>>(xb, WkvT, kv32, T_SEQ, 1024, C_DIM);

  k_qkprep<<<T_SEQ * NH / 4, 256, 0, stream>>>(q32, C_DIM, NH, qnw, 0.08838834764831845f, Qb);
  k_qkprep<<<T_SEQ * NKV / 4, 256, 0, stream>>>(kv32, 1024, NKV, knw, 1.0f, Kb);
  k_vtrans<<<dim3(T_SEQ / 64, 2, NKV), 256, 0, stream>>>(kv32, Vt);

  k_attn<<<dim3(T_SEQ / 64, NH), 256, 0, stream>>>(Qb, Kb, Vt, Yb);

  k_gemm_bt<<<(T_SEQ / 128) * (C_DIM / 128), 256, 0, stream>>>(Yb, WcT, out, T_SEQ, C_DIM, C_DIM);
}

// Round 2
// 455.737 us; speedup vs baseline: 1.6685x; 1.6685x over previous
//
#include <hip/hip_runtime.h>
#include <hip/hip_bf16.h>
#include <math.h>

#define T_SEQ 4096
#define C_DIM 2048
#define NH 16
#define NKV 4
#define HD 128

typedef __attribute__((ext_vector_type(4))) float f32x4;
typedef __attribute__((ext_vector_type(16))) float f32x16;
typedef __attribute__((ext_vector_type(8))) short s16x8;
typedef __hip_bfloat16 bf16;

typedef __attribute__((address_space(3))) void lds_void;
typedef __attribute__((address_space(1))) const void gbl_void;
#define ASYNC16(g, l) __builtin_amdgcn_global_load_lds((gbl_void*)(g), (lds_void*)(l), 16, 0, 0)

// p = exp(50*tanh(s/50)) = exp(50 - 100/(exp(s*0.04)+1)); s'∈[-50,50] -> p∈[2e-22,5.2e21]: no under/overflow
__device__ __forceinline__ float cap_exp(float s) {
  float t = __expf(s * 0.04f);
  float r = __builtin_amdgcn_rcpf(t + 1.0f);
  return __expf(__fmaf_rn(r, -100.0f, 50.0f));
}

__device__ __forceinline__ unsigned packbf(float a, float b) {
  unsigned ua = (unsigned)__bfloat16_as_ushort(__float2bfloat16(a));
  unsigned ub = (unsigned)__bfloat16_as_ushort(__float2bfloat16(b));
  return ua | (ub << 16);
}

// ---------------- fp32 -> bf16 elementwise convert ----------------
__global__ void k_cvt_bf16(const float* __restrict__ in, bf16* __restrict__ out, int n4) {
  int i = blockIdx.x * blockDim.x + threadIdx.x;
  if (i < n4) {
    float4 v = ((const float4*)in)[i];
    union { bf16 h[4]; short4 s; } u;
    u.h[0] = __float2bfloat16(v.x);
    u.h[1] = __float2bfloat16(v.y);
    u.h[2] = __float2bfloat16(v.z);
    u.h[3] = __float2bfloat16(v.w);
    ((short4*)out)[i] = u.s;
  }
}

// ---------------- transpose + convert: in [K][N] f32 -> out [N][K] bf16 ----
__global__ void k_transpose_cvt(const float* __restrict__ in, bf16* __restrict__ out,
                                int K, int N) {
  __shared__ float tile[64][65];
  int n0 = blockIdx.x * 64, k0 = blockIdx.y * 64;
  int c = threadIdx.x & 63, r0 = threadIdx.x >> 6;
#pragma unroll
  for (int it = 0; it < 16; ++it) {
    int r = it * 4 + r0;
    tile[r][c] = in[(size_t)(k0 + r) * N + (n0 + c)];
  }
  __syncthreads();
#pragma unroll
  for (int it = 0; it < 16; ++it) {
    int r = it * 4 + r0;
    out[(size_t)(n0 + r) * K + (k0 + c)] = __float2bfloat16(tile[c][r]);
  }
}

// ---------------- GEMM: C[M][N] = A[M][K] * Bt[N][K]^T  (bf16 in, f32 out) --
// 128x128 tile, BK=64, 256 threads (4 waves as 2x2); global_load_lds staging
__global__ __launch_bounds__(256) void k_gemm_bt(
    const bf16* __restrict__ A, const bf16* __restrict__ Bt, float* __restrict__ C,
    int M, int N, int K) {
  __shared__ __align__(16) bf16 As[128 * 64];
  __shared__ __align__(16) bf16 Bs[128 * 64];
  int nTilesN = N >> 7;
  int bm = blockIdx.x / nTilesN, bn = blockIdx.x % nTilesN;
  int row0 = bm * 128, col0 = bn * 128;
  int tid = threadIdx.x, lane = tid & 63, wid = tid >> 6;
  int wm = wid >> 1, wn = wid & 1;
  int l15 = lane & 15, l4 = lane >> 4;
  f32x4 acc[4][4] = {};
  int srow = lane >> 3;      // 0..7 within 8-row chunk
  int schk = lane & 7;       // 16B chunk within row
  for (int kt = 0; kt < (K >> 6); ++kt) {
    const bf16* Ab = A + (size_t)row0 * K + kt * 64;
    const bf16* Bb = Bt + (size_t)col0 * K + kt * 64;
#pragma unroll
    for (int it = 0; it < 4; ++it) {
      int t = wid * 4 + it;
      ASYNC16(Ab + (size_t)(8 * t + srow) * K + schk * 8, As + t * 512);
      ASYNC16(Bb + (size_t)(8 * t + srow) * K + schk * 8, Bs + t * 512);
    }
    __syncthreads();
#pragma unroll
    for (int ks = 0; ks < 2; ++ks) {
      s16x8 af[4], bfr[4];
#pragma unroll
      for (int m = 0; m < 4; ++m)
        af[m] = *(const s16x8*)(As + (wm * 64 + m * 16 + l15) * 64 + ks * 32 + l4 * 8);
#pragma unroll
      for (int n = 0; n < 4; ++n)
        bfr[n] = *(const s16x8*)(Bs + (wn * 64 + n * 16 + l15) * 64 + ks * 32 + l4 * 8);
#pragma unroll
      for (int m = 0; m < 4; ++m)
#pragma unroll
        for (int n = 0; n < 4; ++n)
          acc[m][n] = __builtin_amdgcn_mfma_f32_16x16x32_bf16(af[m], bfr[n], acc[m][n], 0, 0, 0);
    }
    __syncthreads();
  }
#pragma unroll
  for (int m = 0; m < 4; ++m)
#pragma unroll
    for (int n = 0; n < 4; ++n)
#pragma unroll
      for (int r = 0; r < 4; ++r) {
        int rr = row0 + wm * 64 + m * 16 + l4 * 4 + r;
        int cc = col0 + wn * 64 + n * 16 + l15;
        C[(size_t)rr * N + cc] = acc[m][n][r];
      }
}

// ---------------- RMSNorm + RoPE prep: one wave per (t, head) row ----------
__global__ void k_qkprep(const float* __restrict__ src, int rowStride, int nh,
                         const float* __restrict__ w, float outScale,
                         bf16* __restrict__ out) {
  int idx = blockIdx.x * 4 + (threadIdx.x >> 6);
  int lane = threadIdx.x & 63;
  int t = idx / nh;
  int h = idx & (nh - 1);
  const float* s = src + (size_t)t * rowStride + h * HD;
  float x1 = s[lane], x2 = s[lane + 64];
  float ss = x1 * x1 + x2 * x2;
#pragma unroll
  for (int m = 1; m < 64; m <<= 1) ss += __shfl_xor(ss, m);
  float rs = rsqrtf(ss * (1.0f / 128.0f) + 1e-6f);
  x1 *= rs * w[lane];
  x2 *= rs * w[lane + 64];
  float invf = expf(-(float)lane * 0.14391156831212787f);  // ln(10000)/64
  float fr = (float)t * invf;
  float sv, cv;
  sincosf(fr, &sv, &cv);
  float y1 = (x1 * cv + x2 * sv) * outScale;
  float y2 = (-x1 * sv + x2 * cv) * outScale;
  bf16* dst = out + ((size_t)h * T_SEQ + t) * HD;
  dst[lane] = __float2bfloat16(y1);
  dst[lane + 64] = __float2bfloat16(y2);
}

// ---------------- V transpose: kv32[t][512 + hk*128 + d] -> Vt[hk][d][t] ----
__global__ void k_vtrans(const float* __restrict__ kv32, bf16* __restrict__ Vt) {
  __shared__ float tile[64][65];
  int t0 = blockIdx.x * 64, d0 = blockIdx.y * 64, hk = blockIdx.z;
  int c = threadIdx.x & 63, r0 = threadIdx.x >> 6;
#pragma unroll
  for (int it = 0; it < 16; ++it) {
    int r = it * 4 + r0;
    tile[r][c] = kv32[(size_t)(t0 + r) * 1024 + 512 + hk * 128 + d0 + c];
  }
  __syncthreads();
#pragma unroll
  for (int it = 0; it < 16; ++it) {
    int r = it * 4 + r0;
    Vt[((size_t)hk * 128 + d0 + r) * T_SEQ + (t0 + c)] = __float2bfloat16(tile[c][r]);
  }
}

// ---------------- causal GQA flash attention, 32x32 swapped-QK^T -----------
// Qb [NH][T][128] (pre-scaled), Kb [NKV][T][128], Vt [NKV][128][T], Y [T][C] bf16
// Block: 4 waves x 32 q-rows = 128 q; KV tile 64 (2 sub-tiles of 32).
// Static-max softmax: p = exp(softcap(s)), bounded by e^50; row sum reduced once at end.
__global__ __launch_bounds__(256) void k_attn2(
    const bf16* __restrict__ Qb, const bf16* __restrict__ Kb,
    const bf16* __restrict__ Vt, bf16* __restrict__ Y) {
  __shared__ __align__(16) bf16 Ks[64 * 128];  // [kv][d], 16-chunk XOR swizzle (r&15)
  __shared__ __align__(16) bf16 Vs[128 * 64];  // [d][kv], 8-chunk XOR swizzle (d&7)
  __shared__ float sInv[4][32];
  int bx = blockIdx.x;
  int qb = 31 - (bx >> 4);        // heavy blocks first
  int h = bx & 15;
  int hk = h >> 2;
  int tid = threadIdx.x, lane = tid & 63, w = tid >> 6;
  int l31 = lane & 31, hi = lane >> 5;
  int qrow0b = qb * 128;
  int qrow0w = qrow0b + w * 32;
  int wqmax = qrow0w + 31;

  const bf16* Kbase = Kb + (size_t)hk * T_SEQ * HD;
  const bf16* Vbase = Vt + (size_t)hk * HD * T_SEQ;

  // Q fragments: B-operand of QK^T: lane holds Q[q0+l31][s*16 + hi*8 .. +8]
  s16x8 qf[8];
  {
    const bf16* Qp = Qb + ((size_t)h * T_SEQ + qrow0w + l31) * HD + hi * 8;
#pragma unroll
    for (int s = 0; s < 8; ++s) qf[s] = *(const s16x8*)(Qp + s * 16);
  }
  f32x16 acc[4] = {};   // PV accumulator: 4 d-blocks of 32
  float lp = 0.f;       // partial row-sum (this lane's half-row share)

  int nt = qrow0b / 64 + 2;
  for (int kt = 0; kt < nt; ++kt) {
    int kv0 = kt * 64;
    // ---- stage K[64][128] and Vt[128][64] via global_load_lds, pre-swizzled source
#pragma unroll
    for (int i = 0; i < 4; ++i) {
      int j = w * 4 + i;
      int rk = j * 4 + (lane >> 4);
      int chk = (lane & 15) ^ (rk & 15);
      ASYNC16(Kbase + (size_t)(kv0 + rk) * HD + chk * 8, Ks + j * 512);
      int dv = j * 8 + (lane >> 3);
      int chv = (lane & 7) ^ (dv & 7);
      ASYNC16(Vbase + (size_t)dv * T_SEQ + kv0 + chv * 8, Vs + j * 512);
    }
    __syncthreads();
#pragma unroll
    for (int sub = 0; sub < 2; ++sub) {
      int kv0s = kv0 + sub * 32;
      if (kv0s <= wqmax) {   // wave-uniform
        // ---- S^T = K Q^T (32kv x 32q), 8 mfma over d=128
        f32x16 sacc = {};
#pragma unroll
        for (int s = 0; s < 8; ++s) {
          int r = sub * 32 + l31;
          s16x8 kf = *(const s16x8*)(Ks + r * 128 + (((2 * s + hi) ^ (r & 15)) * 8));
          sacc = __builtin_amdgcn_mfma_f32_32x32x16_bf16(kf, qf[s], sacc, 0, 0, 0);
        }
        // ---- softcap+exp (+mask near diagonal); lane owns q=l31, kv=crow(r,hi)
        float p[16];
        bool needmask = (kv0s + 31 > qrow0w);
        int qidx = qrow0w + l31;
#pragma unroll
        for (int r = 0; r < 16; ++r) {
          int kvl = (r & 3) + 8 * (r >> 2) + 4 * hi;
          float pe = cap_exp(sacc[r]);
          if (needmask) pe = (kv0s + kvl > qidx) ? 0.f : pe;
          p[r] = pe;
          lp += pe;
        }
        // ---- pack P to bf16, cross-half exchange -> PV A-fragments
        unsigned u[8];
#pragma unroll
        for (int i2 = 0; i2 < 8; ++i2) u[i2] = packbf(p[2 * i2], p[2 * i2 + 1]);
        s16x8 pa[2];
#pragma unroll
        for (int s2 = 0; s2 < 2; ++s2) {
          int b = s2 * 4;
          unsigned t0 = (unsigned)__shfl_xor((int)u[b + 0], 32);
          unsigned t1 = (unsigned)__shfl_xor((int)u[b + 1], 32);
          unsigned t2 = (unsigned)__shfl_xor((int)u[b + 2], 32);
          unsigned t3 = (unsigned)__shfl_xor((int)u[b + 3], 32);
          union { unsigned wd[4]; s16x8 v; } cv;
          cv.wd[0] = hi ? t2 : u[b + 0];
          cv.wd[1] = hi ? t3 : u[b + 1];
          cv.wd[2] = hi ? u[b + 2] : t0;
          cv.wd[3] = hi ? u[b + 3] : t1;
          pa[s2] = cv.v;
        }
        // ---- PV: acc[db] += P(32q x 32kv) * V(32kv x 32d)
#pragma unroll
        for (int db = 0; db < 4; ++db) {
          int d = db * 32 + l31;
#pragma unroll
          for (int s2 = 0; s2 < 2; ++s2) {
            int lch = sub * 4 + s2 * 2 + hi;
            s16x8 vf = *(const s16x8*)(Vs + d * 64 + ((lch ^ (d & 7)) * 8));
            acc[db] = __builtin_amdgcn_mfma_f32_32x32x16_bf16(pa[s2], vf, acc[db], 0, 0, 0);
          }
        }
      }
    }
    __syncthreads();
  }
  // ---- finalize: row sum across halves, reciprocal, epilogue
  float ltot = lp + __shfl_xor(lp, 32);
  if (hi == 0) sInv[w][l31] = 1.0f / ltot;
  // same-wave LDS RAW: compiler inserts lgkmcnt wait; no barrier needed (sInv[w] is wave-private)
#pragma unroll
  for (int db = 0; db < 4; ++db) {
#pragma unroll
    for (int r = 0; r < 16; ++r) {
      int qrow = (r & 3) + 8 * (r >> 2) + 4 * hi;
      float val = acc[db][r] * sInv[w][qrow];
      Y[(size_t)(qrow0w + qrow) * C_DIM + h * HD + db * 32 + l31] = __float2bfloat16(val);
    }
  }
}

extern "C" void kernel_launch(void* const* d_in, const int* in_sizes, int n_in,
                              void* d_out, int out_size, void* d_ws, size_t ws_size,
                              hipStream_t stream) {
  const float* x = (const float*)d_in[0];
  const float* Wq = (const float*)d_in[1];
  const float* Wkv = (const float*)d_in[2];
  const float* Wc = (const float*)d_in[3];
  const float* qnw = (const float*)d_in[4];
  const float* knw = (const float*)d_in[5];
  float* out = (float*)d_out;

  char* ws = (char*)d_ws;
  size_t off = 0;
  auto alloc = [&](size_t b) { void* p = ws + off; off += (b + 255) & ~(size_t)255; return p; };

  bf16* xb = (bf16*)alloc((size_t)T_SEQ * C_DIM * 2);
  bf16* WqT = (bf16*)alloc((size_t)C_DIM * C_DIM * 2);
  bf16* WkvT = (bf16*)alloc((size_t)1024 * C_DIM * 2);
  bf16* WcT = (bf16*)alloc((size_t)C_DIM * C_DIM * 2);
  float* kv32 = (float*)alloc((size_t)T_SEQ * 1024 * 4);
  bf16* Qb = (bf16*)alloc((size_t)NH * T_SEQ * HD * 2);
  bf16* Kb = (bf16*)alloc((size_t)NKV * T_SEQ * HD * 2);
  bf16* Vt = (bf16*)alloc((size_t)NKV * HD * T_SEQ * 2);
  bf16* Yb = (bf16*)alloc((size_t)T_SEQ * C_DIM * 2);
  float* q32 = out;  // reuse output buffer as scratch for pre-norm q

  k_cvt_bf16<<<(T_SEQ * C_DIM / 4 + 255) / 256, 256, 0, stream>>>(x, xb, T_SEQ * C_DIM / 4);
  k_transpose_cvt<<<dim3(C_DIM / 64, C_DIM / 64), 256, 0, stream>>>(Wq, WqT, C_DIM, C_DIM);
  k_transpose_cvt<<<dim3(1024 / 64, C_DIM / 64), 256, 0, stream>>>(Wkv, WkvT, C_DIM, 1024);
  k_transpose_cvt<<<dim3(C_DIM / 64, C_DIM / 64), 256, 0, stream>>>(Wc, WcT, C_DIM, C_DIM);

  k_gemm_bt<<<(T_SEQ / 128) * (C_DIM / 128), 256, 0, stream>>>(xb, WqT, q32, T_SEQ, C_DIM, C_DIM);
  k_gemm_bt<<<(T_SEQ / 128) * (1024 / 128), 256, 0, stream>>>(xb, WkvT, kv32, T_SEQ, 1024, C_DIM);

  k_qkprep<<<T_SEQ * NH / 4, 256, 0, stream>>>(q32, C_DIM, NH, qnw, 0.08838834764831845f, Qb);
  k_qkprep<<<T_SEQ * NKV / 4, 256, 0, stream>>>(kv32, 1024, NKV, knw, 1.0f, Kb);
  k_vtrans<<<dim3(T_SEQ / 64, 2, NKV), 256, 0, stream>>>(kv32, Vt);

  k_attn2<<<dim3(512), 256, 0, stream>>>(Qb, Kb, Vt, Yb);

  k_gemm_bt<<<(T_SEQ / 128) * (C_DIM / 128), 256, 0, stream>>>(Yb, WcT, out, T_SEQ, C_DIM, C_DIM);
}

// Round 4
// 438.175 us; speedup vs baseline: 1.7353x; 1.0401x over previous
//
#include <hip/hip_runtime.h>
#include <hip/hip_bf16.h>
#include <math.h>

#define T_SEQ 4096
#define C_DIM 2048
#define NH 16
#define NKV 4
#define HD 128

typedef __attribute__((ext_vector_type(4))) float f32x4;
typedef __attribute__((ext_vector_type(16))) float f32x16;
typedef __attribute__((ext_vector_type(8))) short s16x8;
typedef __hip_bfloat16 bf16;

typedef __attribute__((address_space(3))) void lds_void;
typedef __attribute__((address_space(1))) const void gbl_void;
#define ASYNC16(g, l) __builtin_amdgcn_global_load_lds((gbl_void*)(g), (lds_void*)(l), 16, 0, 0)

// p = exp(50*tanh(s/50)) = exp(50 - 100/(exp(s*0.04)+1)); |s| realistically < 40
__device__ __forceinline__ float cap_exp(float s) {
  float t = __expf(s * 0.04f);
  float r = __builtin_amdgcn_rcpf(t + 1.0f);
  return __expf(__fmaf_rn(r, -100.0f, 50.0f));
}

__device__ __forceinline__ unsigned packbf(float a, float b) {
  unsigned ua = (unsigned)__bfloat16_as_ushort(__float2bfloat16(a));
  unsigned ub = (unsigned)__bfloat16_as_ushort(__float2bfloat16(b));
  return ua | (ub << 16);
}

// ---------------- fp32 -> bf16 elementwise convert ----------------
__global__ void k_cvt_bf16(const float* __restrict__ in, bf16* __restrict__ out, int n4) {
  int i = blockIdx.x * blockDim.x + threadIdx.x;
  if (i < n4) {
    float4 v = ((const float4*)in)[i];
    union { bf16 h[4]; short4 s; } u;
    u.h[0] = __float2bfloat16(v.x);
    u.h[1] = __float2bfloat16(v.y);
    u.h[2] = __float2bfloat16(v.z);
    u.h[3] = __float2bfloat16(v.w);
    ((short4*)out)[i] = u.s;
  }
}

// ---------------- transpose + convert: in [K][N] f32 -> out [N][K] bf16 ----
__global__ void k_transpose_cvt(const float* __restrict__ in, bf16* __restrict__ out,
                                int K, int N) {
  __shared__ float tile[64][65];
  int n0 = blockIdx.x * 64, k0 = blockIdx.y * 64;
  int c = threadIdx.x & 63, r0 = threadIdx.x >> 6;
#pragma unroll
  for (int it = 0; it < 16; ++it) {
    int r = it * 4 + r0;
    tile[r][c] = in[(size_t)(k0 + r) * N + (n0 + c)];
  }
  __syncthreads();
#pragma unroll
  for (int it = 0; it < 16; ++it) {
    int r = it * 4 + r0;
    out[(size_t)(n0 + r) * K + (k0 + c)] = __float2bfloat16(tile[c][r]);
  }
}

// ---------------- RoPE cos/sin table: [T][64] each ----------------
__global__ void k_rope_table(float* __restrict__ ctab, float* __restrict__ stab) {
  int idx = blockIdx.x * blockDim.x + threadIdx.x;  // t*64 + i
  int t = idx >> 6, i = idx & 63;
  float invf = __expf(-(float)i * 0.14391156831212787f);  // ln(10000)/64
  float fr = (float)t * invf;
  float sv, cv;
  __sincosf(fr, &sv, &cv);
  ctab[idx] = cv;
  stab[idx] = sv;
}

// ---------------- GEMM: A[M][K] * Bt[N][K]^T, dual-target fp32 epilogue -----
// 128x128 tile, BK=64, 256 threads (4 waves as 2x2); global_load_lds staging.
// cols < split -> Cq (ld ldq); cols >= split -> Ckv at col-split (ld ldkv)
__global__ __launch_bounds__(256) void k_gemm_bt(
    const bf16* __restrict__ A, const bf16* __restrict__ Bt,
    float* __restrict__ Cq, int ldq, float* __restrict__ Ckv, int ldkv, int split,
    int M, int N, int K) {
  __shared__ __align__(16) bf16 As[128 * 64];
  __shared__ __align__(16) bf16 Bs[128 * 64];
  int nTilesN = N >> 7;
  int bm = blockIdx.x / nTilesN, bn = blockIdx.x % nTilesN;
  int row0 = bm * 128, col0 = bn * 128;
  int tid = threadIdx.x, lane = tid & 63, wid = tid >> 6;
  int wm = wid >> 1, wn = wid & 1;
  int l15 = lane & 15, l4 = lane >> 4;
  f32x4 acc[4][4] = {};
  int srow = lane >> 3;
  int schk = lane & 7;
  for (int kt = 0; kt < (K >> 6); ++kt) {
    const bf16* Ab = A + (size_t)row0 * K + kt * 64;
    const bf16* Bb = Bt + (size_t)col0 * K + kt * 64;
#pragma unroll
    for (int it = 0; it < 4; ++it) {
      int t = wid * 4 + it;
      ASYNC16(Ab + (size_t)(8 * t + srow) * K + schk * 8, As + t * 512);
      ASYNC16(Bb + (size_t)(8 * t + srow) * K + schk * 8, Bs + t * 512);
    }
    __syncthreads();
#pragma unroll
    for (int ks = 0; ks < 2; ++ks) {
      s16x8 af[4], bfr[4];
#pragma unroll
      for (int m = 0; m < 4; ++m)
        af[m] = *(const s16x8*)(As + (wm * 64 + m * 16 + l15) * 64 + ks * 32 + l4 * 8);
#pragma unroll
      for (int n = 0; n < 4; ++n)
        bfr[n] = *(const s16x8*)(Bs + (wn * 64 + n * 16 + l15) * 64 + ks * 32 + l4 * 8);
#pragma unroll
      for (int m = 0; m < 4; ++m)
#pragma unroll
        for (int n = 0; n < 4; ++n)
          acc[m][n] = __builtin_amdgcn_mfma_f32_16x16x32_bf16(af[m], bfr[n], acc[m][n], 0, 0, 0);
    }
    __syncthreads();
  }
  float* Cbase;
  int ldc, ccoff;
  if (col0 < split) { Cbase = Cq; ldc = ldq; ccoff = 0; }
  else { Cbase = Ckv; ldc = ldkv; ccoff = split; }
#pragma unroll
  for (int m = 0; m < 4; ++m)
#pragma unroll
    for (int n = 0; n < 4; ++n)
#pragma unroll
      for (int r = 0; r < 4; ++r) {
        int rr = row0 + wm * 64 + m * 16 + l4 * 4 + r;
        int cc = col0 + wn * 64 + n * 16 + l15 - ccoff;
        Cbase[(size_t)rr * ldc + cc] = acc[m][n][r];
      }
}

// ---------------- RMSNorm + RoPE prep (table-driven) ----------------
__global__ void k_qkprep(const float* __restrict__ src, int rowStride, int nh,
                         const float* __restrict__ w, float outScale,
                         const float* __restrict__ ctab, const float* __restrict__ stab,
                         bf16* __restrict__ out) {
  int idx = blockIdx.x * 4 + (threadIdx.x >> 6);
  int lane = threadIdx.x & 63;
  int t = idx / nh;
  int h = idx & (nh - 1);
  const float* s = src + (size_t)t * rowStride + h * HD;
  float x1 = s[lane], x2 = s[lane + 64];
  float ss = x1 * x1 + x2 * x2;
#pragma unroll
  for (int m = 1; m < 64; m <<= 1) ss += __shfl_xor(ss, m);
  float rs = rsqrtf(ss * (1.0f / 128.0f) + 1e-6f);
  x1 *= rs * w[lane];
  x2 *= rs * w[lane + 64];
  float cv = ctab[t * 64 + lane], sv = stab[t * 64 + lane];
  float y1 = (x1 * cv + x2 * sv) * outScale;
  float y2 = (-x1 * sv + x2 * cv) * outScale;
  bf16* dst = out + ((size_t)h * T_SEQ + t) * HD;
  dst[lane] = __float2bfloat16(y1);
  dst[lane + 64] = __float2bfloat16(y2);
}

// ---------------- V transpose: kv32[t][512 + hk*128 + d] -> Vt[hk][d][t] ----
__global__ void k_vtrans(const float* __restrict__ kv32, bf16* __restrict__ Vt) {
  __shared__ float tile[64][65];
  int t0 = blockIdx.x * 64, d0 = blockIdx.y * 64, hk = blockIdx.z;
  int c = threadIdx.x & 63, r0 = threadIdx.x >> 6;
#pragma unroll
  for (int it = 0; it < 16; ++it) {
    int r = it * 4 + r0;
    tile[r][c] = kv32[(size_t)(t0 + r) * 1024 + 512 + hk * 128 + d0 + c];
  }
  __syncthreads();
#pragma unroll
  for (int it = 0; it < 16; ++it) {
    int r = it * 4 + r0;
    Vt[((size_t)hk * 128 + d0 + r) * T_SEQ + (t0 + c)] = __float2bfloat16(tile[c][r]);
  }
}

// ---------------- causal GQA flash attention, parity-split ------------------
// Block: 64 q-rows x 1 head; 4 waves = 2 q-subtiles x 2 kv-parities.
// Static-max softmax => parity partials are directly summable (acc+acc, l+l).
union AttnLds {
  struct { __align__(16) bf16 K[64 * 128]; __align__(16) bf16 V[128 * 64]; } st;
  float mrg[2][64 * 65];  // parity-1 acc spill (stride 65: conflict-free)
};
__global__ __launch_bounds__(256) void k_attn3(
    const bf16* __restrict__ Qb, const bf16* __restrict__ Kb,
    const bf16* __restrict__ Vt, bf16* __restrict__ Y) {
  __shared__ AttnLds lds;
  __shared__ float lpbuf[2][32];
  __shared__ float invbuf[2][32];
  int bx = blockIdx.x;
  int qb = 63 - (bx >> 4);  // heavy blocks first
  int h = bx & 15;
  int hk = h >> 2;
  int tid = threadIdx.x, lane = tid & 63, w = tid >> 6;
  int l31 = lane & 31, hi = lane >> 5;
  int qsub = w >> 1, p = w & 1;
  int q0 = qb * 64;
  int qw0 = q0 + qsub * 32;

  bf16* Ks = lds.st.K;
  bf16* Vs = lds.st.V;
  const bf16* Kbase = Kb + (size_t)hk * T_SEQ * HD;
  const bf16* Vbase = Vt + (size_t)hk * HD * T_SEQ;

  // Q fragments (B-operand): lane holds Q[qw0+l31][s*16 + hi*8 .. +8]
  s16x8 qf[8];
  {
    const bf16* Qp = Qb + ((size_t)h * T_SEQ + qw0 + l31) * HD + hi * 8;
#pragma unroll
    for (int s = 0; s < 8; ++s) qf[s] = *(const s16x8*)(Qp + s * 16);
  }
  f32x16 acc[4] = {};  // PV accumulator: 4 d-blocks of 32
  float lp = 0.f;      // partial row-sum

  for (int jj = 0; jj <= qb; ++jj) {
    int kv0 = jj * 64;
    // stage K[64][128], Vt[128][64] via global_load_lds, pre-swizzled source
#pragma unroll
    for (int i = 0; i < 4; ++i) {
      int j = w * 4 + i;
      int rk = j * 4 + (lane >> 4);
      int chk = (lane & 15) ^ (rk & 15);
      ASYNC16(Kbase + (size_t)(kv0 + rk) * HD + chk * 8, Ks + j * 512);
      int dv = j * 8 + (lane >> 3);
      int chv = (lane & 7) ^ (dv & 7);
      ASYNC16(Vbase + (size_t)dv * T_SEQ + kv0 + chv * 8, Vs + j * 512);
    }
    __syncthreads();
    int kvs = kv0 + p * 32;
    if (kvs <= qw0 + 31) {  // wave-uniform
      // S^T = K Q^T (32kv x 32q) over d=128
      f32x16 sacc = {};
      int r = p * 32 + l31;
#pragma unroll
      for (int s = 0; s < 8; ++s) {
        s16x8 kf = *(const s16x8*)(Ks + r * 128 + (((2 * s + hi) ^ (r & 15)) * 8));
        sacc = __builtin_amdgcn_mfma_f32_32x32x16_bf16(kf, qf[s], sacc, 0, 0, 0);
      }
      // softcap+exp (+mask only on the diagonal subtile)
      float pv[16];
      bool needmask = (kvs == qw0);
#pragma unroll
      for (int rr = 0; rr < 16; ++rr) {
        int kvl = (rr & 3) + 8 * (rr >> 2) + 4 * hi;
        float pe = cap_exp(sacc[rr]);
        if (needmask) pe = (kvl > l31) ? 0.f : pe;
        pv[rr] = pe;
        lp += pe;
      }
      // pack P to bf16, cross-half exchange -> PV A-fragments
      unsigned u[8];
#pragma unroll
      for (int i2 = 0; i2 < 8; ++i2) u[i2] = packbf(pv[2 * i2], pv[2 * i2 + 1]);
      s16x8 pa[2];
#pragma unroll
      for (int s2 = 0; s2 < 2; ++s2) {
        int b = s2 * 4;
        unsigned t0 = (unsigned)__shfl_xor((int)u[b + 0], 32);
        unsigned t1 = (unsigned)__shfl_xor((int)u[b + 1], 32);
        unsigned t2 = (unsigned)__shfl_xor((int)u[b + 2], 32);
        unsigned t3 = (unsigned)__shfl_xor((int)u[b + 3], 32);
        union { unsigned wd[4]; s16x8 v; } cv;
        cv.wd[0] = hi ? t2 : u[b + 0];
        cv.wd[1] = hi ? t3 : u[b + 1];
        cv.wd[2] = hi ? u[b + 2] : t0;
        cv.wd[3] = hi ? u[b + 3] : t1;
        pa[s2] = cv.v;
      }
      // PV: acc[db] += P(32q x 32kv) * V(32kv x 32d)
#pragma unroll
      for (int db = 0; db < 4; ++db) {
        int d = db * 32 + l31;
#pragma unroll
        for (int s2 = 0; s2 < 2; ++s2) {
          int lch = p * 4 + s2 * 2 + hi;
          s16x8 vf = *(const s16x8*)(Vs + d * 64 + ((lch ^ (d & 7)) * 8));
          acc[db] = __builtin_amdgcn_mfma_f32_32x32x16_bf16(pa[s2], vf, acc[db], 0, 0, 0);
        }
      }
    }
    __syncthreads();
  }
  // ---- merge parity partials, finalize
  float lps = lp + __shfl_xor(lp, 32);
  if (p == 1) {
    if (hi == 0) lpbuf[qsub][l31] = lps;
#pragma unroll
    for (int db = 0; db < 4; ++db)
#pragma unroll
      for (int rr = 0; rr < 16; ++rr)
        lds.mrg[qsub][lane * 65 + db * 16 + rr] = acc[db][rr];
  }
  __syncthreads();
  if (p == 0) {
    float ltot = lps + lpbuf[qsub][l31];
    if (hi == 0) invbuf[qsub][l31] = 1.0f / ltot;  // same-wave LDS RAW
#pragma unroll
    for (int db = 0; db < 4; ++db)
#pragma unroll
      for (int rr = 0; rr < 16; ++rr) {
        int qrow = (rr & 3) + 8 * (rr >> 2) + 4 * hi;
        float val = (acc[db][rr] + lds.mrg[qsub][lane * 65 + db * 16 + rr]) * invbuf[qsub][qrow];
        Y[(size_t)(qw0 + qrow) * C_DIM + h * HD + db * 32 + l31] = __float2bfloat16(val);
      }
  }
}

extern "C" void kernel_launch(void* const* d_in, const int* in_sizes, int n_in,
                              void* d_out, int out_size, void* d_ws, size_t ws_size,
                              hipStream_t stream) {
  const float* x = (const float*)d_in[0];
  const float* Wq = (const float*)d_in[1];
  const float* Wkv = (const float*)d_in[2];
  const float* Wc = (const float*)d_in[3];
  const float* qnw = (const float*)d_in[4];
  const float* knw = (const float*)d_in[5];
  float* out = (float*)d_out;

  char* ws = (char*)d_ws;
  size_t off = 0;
  auto alloc = [&](size_t b) { void* p = ws + off; off += (b + 255) & ~(size_t)255; return p; };

  bf16* xb = (bf16*)alloc((size_t)T_SEQ * C_DIM * 2);
  bf16* WqT = (bf16*)alloc((size_t)C_DIM * C_DIM * 2);   // contiguous with WkvT:
  bf16* WkvT = (bf16*)alloc((size_t)1024 * C_DIM * 2);   // fused B = [3072][2048]
  bf16* WcT = (bf16*)alloc((size_t)C_DIM * C_DIM * 2);
  float* kv32 = (float*)alloc((size_t)T_SEQ * 1024 * 4);
  bf16* Qb = (bf16*)alloc((size_t)NH * T_SEQ * HD * 2);
  bf16* Kb = (bf16*)alloc((size_t)NKV * T_SEQ * HD * 2);
  bf16* Vt = (bf16*)alloc((size_t)NKV * HD * T_SEQ * 2);
  bf16* Yb = (bf16*)alloc((size_t)T_SEQ * C_DIM * 2);
  float* ctab = (float*)alloc((size_t)T_SEQ * 64 * 4);
  float* stab = (float*)alloc((size_t)T_SEQ * 64 * 4);
  float* q32 = out;  // reuse output buffer as scratch for pre-norm q

  k_cvt_bf16<<<(T_SEQ * C_DIM / 4 + 255) / 256, 256, 0, stream>>>(x, xb, T_SEQ * C_DIM / 4);
  k_transpose_cvt<<<dim3(C_DIM / 64, C_DIM / 64), 256, 0, stream>>>(Wq, WqT, C_DIM, C_DIM);
  k_transpose_cvt<<<dim3(1024 / 64, C_DIM / 64), 256, 0, stream>>>(Wkv, WkvT, C_DIM, 1024);
  k_transpose_cvt<<<dim3(C_DIM / 64, C_DIM / 64), 256, 0, stream>>>(Wc, WcT, C_DIM, C_DIM);
  k_rope_table<<<T_SEQ * 64 / 256, 256, 0, stream>>>(ctab, stab);

  // fused QKV projection: N = 2048 (q -> q32) + 1024 (kv -> kv32)
  k_gemm_bt<<<(T_SEQ / 128) * (3072 / 128), 256, 0, stream>>>(
      xb, WqT, q32, C_DIM, kv32, 1024, C_DIM, T_SEQ, 3072, C_DIM);

  k_qkprep<<<T_SEQ * NH / 4, 256, 0, stream>>>(q32, C_DIM, NH, qnw, 0.08838834764831845f, ctab, stab, Qb);
  k_qkprep<<<T_SEQ * NKV / 4, 256, 0, stream>>>(kv32, 1024, NKV, knw, 1.0f, ctab, stab, Kb);
  k_vtrans<<<dim3(T_SEQ / 64, 2, NKV), 256, 0, stream>>>(kv32, Vt);

  k_attn3<<<dim3(1024), 256, 0, stream>>>(Qb, Kb, Vt, Yb);

  k_gemm_bt<<<(T_SEQ / 128) * (C_DIM / 128), 256, 0, stream>>>(
      Yb, WcT, out, C_DIM, nullptr, 0, C_DIM, T_SEQ, C_DIM, C_DIM);
}